// Round 1
// baseline (44.035 us; speedup 1.0000x reference)
//
#include <hip/hip_runtime.h>
#include <math.h>

#define CC 8
#define VV 2
#define BB 4096
#define DD 512

constexpr float INV_T    = 10.0f;     // 1 / 0.1
constexpr float NORM_EPS = 1e-12f;
constexpr int   NSLOT       = CC * VV;   // 16 vectors per batch column
constexpr int   SLOT_STRIDE = BB * DD;   // elements between (c,v) slots

__device__ __forceinline__ float dot8(const float4& x0, const float4& x1,
                                      const float4& y0, const float4& y1) {
    float s = x0.x * y0.x;
    s = fmaf(x0.y, y0.y, s);
    s = fmaf(x0.z, y0.z, s);
    s = fmaf(x0.w, y0.w, s);
    s = fmaf(x1.x, y1.x, s);
    s = fmaf(x1.y, y1.y, s);
    s = fmaf(x1.z, y1.z, s);
    s = fmaf(x1.w, y1.w, s);
    return s;
}

// Reduce 8 independent per-lane partial sums across the 64-lane wave.
// Returns: lane (8g + r) holds the full wave-sum of scalar r.
__device__ __forceinline__ float reduce8(float p[8], int lane) {
#pragma unroll
    for (int i = 0; i < 8; ++i) {
        p[i] += __shfl_xor(p[i], 1);
        p[i] += __shfl_xor(p[i], 2);
        p[i] += __shfl_xor(p[i], 4);
    }
    const int r = lane & 7;
    float a0 = (r & 1) ? p[1] : p[0];
    float a1 = (r & 1) ? p[3] : p[2];
    float a2 = (r & 1) ? p[5] : p[4];
    float a3 = (r & 1) ? p[7] : p[6];
    float b0 = (r & 2) ? a1 : a0;
    float b1 = (r & 2) ? a3 : a2;
    float v  = (r & 4) ? b1 : b0;
    v += __shfl_xor(v, 8);
    v += __shfl_xor(v, 16);
    v += __shfl_xor(v, 32);
    return v;
}

__global__ __launch_bounds__(256)
void ntxent_main(const float* __restrict__ inp, float* __restrict__ out) {
    const int lane = threadIdx.x & 63;
    const int wv   = threadIdx.x >> 6;      // wave within block: 0..3
    const int b    = blockIdx.x * 4 + wv;   // batch column

    __shared__ float s_sim[4][CC][NSLOT + 1];  // raw anchor·target dots (pad 17)
    __shared__ float s_selfodd[4][CC];         // self-dots of odd (v=1) slots
    __shared__ float s_inv[4][NSLOT];          // 1/max(norm,eps)
    __shared__ float s_pos[4][CC];             // sim_pos[a]
    __shared__ float s_wsum[4];

    const float* base = inp + (size_t)b * DD;

    // Load all 16 vectors for this b: lane owns elems {4L..4L+3} U {256+4L..}
    float4 vlo[NSLOT], vhi[NSLOT];
#pragma unroll
    for (int s = 0; s < NSLOT; ++s) {
        const float4* p = reinterpret_cast<const float4*>(base + (size_t)s * SLOT_STRIDE);
        vlo[s] = p[lane];
        vhi[s] = p[64 + lane];
    }

    // 8 anchors (slots 2a) x 16 targets raw dots
#pragma unroll
    for (int s = 0; s < NSLOT; ++s) {
        float p[8];
#pragma unroll
        for (int a = 0; a < 8; ++a)
            p[a] = dot8(vlo[2 * a], vhi[2 * a], vlo[s], vhi[s]);
        float v = reduce8(p, lane);
        if (lane < 8) s_sim[wv][lane][s] = v;  // s_sim[a][s]; diag s=2a is ||anchor||^2
    }
    // self-dots of the 8 odd (view-1) slots
    {
        float p[8];
#pragma unroll
        for (int a = 0; a < 8; ++a)
            p[a] = dot8(vlo[2 * a + 1], vhi[2 * a + 1], vlo[2 * a + 1], vhi[2 * a + 1]);
        float v = reduce8(p, lane);
        if (lane < 8) s_selfodd[wv][lane] = v;
    }
    __syncthreads();

    // inverse norms
    if (lane < NSLOT) {
        const int t = lane;
        const float d2 = (t & 1) ? s_selfodd[wv][t >> 1] : s_sim[wv][t >> 1][t];
        s_inv[wv][t] = 1.0f / fmaxf(sqrtf(d2), NORM_EPS);
    }
    __syncthreads();
    // sim_pos[a] = normalized dot(anchor a, slot 2a+1) / T
    if (lane < CC) {
        const int a = lane;
        s_pos[wv][a] = s_sim[wv][a][2 * a + 1] * s_inv[wv][2 * a] * s_inv[wv][2 * a + 1] * INV_T;
    }
    __syncthreads();

    // loss_ab = log(1 + sum_{t: t/2 != a} exp(sim[a][t] - sim_pos[a]))
    // lane handles pairs p = lane and lane+64;  a = p>>4, t = p&15
    float ee[2];
#pragma unroll
    for (int h = 0; h < 2; ++h) {
        const int p = lane + 64 * h;
        const int a = p >> 4;
        const int t = p & 15;
        const float sim = s_sim[wv][a][t] * s_inv[wv][2 * a] * s_inv[wv][t] * INV_T;
        const float x = sim - s_pos[wv][a];
        ee[h] = ((t >> 1) == a) ? 0.0f : __expf(x);
    }
    // sum over the 16 t's within each 16-lane group (a is group-uniform)
#pragma unroll
    for (int m = 1; m < 16; m <<= 1) {
        ee[0] += __shfl_xor(ee[0], m);
        ee[1] += __shfl_xor(ee[1], m);
    }
    float l = __logf(1.0f + ee[0]) + __logf(1.0f + ee[1]);
    l += __shfl_xor(l, 16);
    l += __shfl_xor(l, 32);   // l = sum over a=0..7 of loss for this b

    if (lane == 0) s_wsum[wv] = l;
    __syncthreads();
    if (threadIdx.x == 0) {
        const float scale = 1.0f / (float)(CC * BB);
        atomicAdd(out, (s_wsum[0] + s_wsum[1] + s_wsum[2] + s_wsum[3]) * scale);
    }
}

extern "C" void kernel_launch(void* const* d_in, const int* in_sizes, int n_in,
                              void* d_out, int out_size, void* d_ws, size_t ws_size,
                              hipStream_t stream) {
    const float* inp = (const float*)d_in[0];
    float* out = (float*)d_out;
    hipMemsetAsync(out, 0, sizeof(float), stream);
    ntxent_main<<<dim3(BB / 4), dim3(256), 0, stream>>>(inp, out);
}

// Round 3
// 42.460 us; speedup vs baseline: 1.0371x; 1.0371x over previous
//
#include <hip/hip_runtime.h>
#include <hip/hip_bf16.h>
#include <math.h>

#define CC 8
#define BB 4096
#define DD 512
#define SLOT_STRIDE (BB * DD)   // elements between (c,v) slots

constexpr float INV_T    = 10.0f;    // 1 / 0.1
constexpr float NORM_EPS = 1e-12f;

typedef __attribute__((ext_vector_type(8))) short bf16x8;  // 8 bf16 (4 VGPRs)
typedef __attribute__((ext_vector_type(4))) float f32x4;   // 4 fp32 acc

__device__ __forceinline__ short f2bf(float x) {
    union { __hip_bfloat16 h; short s; } u;
    u.h = __float2bfloat16(x);
    return u.s;
}

// One wave per batch column b. The 16 vectors (slots) of column b form
// X (16 x 512). Gram G = X X^T via 16x16x32 bf16 MFMA with A-frag == B-frag
// (identical lane mapping: row/col = lane&15). Because BOTH operands come
// from the same registers, ANY shared element->k permutation cancels:
// G[i][j] = sum_k x_i[perm(k)] * x_j[perm(k)] = dot(x_i, x_j) exactly.
// So we choose the permutation that maximizes coalescing: the 4 kg-lanes of
// a slot consume one full 64B line per load. Norms kept exact in f32.
__global__ __launch_bounds__(256)
void ntxent_mfma(const float* __restrict__ inp, float* __restrict__ out) {
    const int lane = threadIdx.x & 63;
    const int wv   = threadIdx.x >> 6;      // wave in block: 0..3
    const int b    = blockIdx.x * 4 + wv;   // batch column
    const int slot = lane & 15;             // vector index = MFMA row & col
    const int kg   = lane >> 4;             // quarter-wave 0..3

    const float4* p4 = reinterpret_cast<const float4*>(
        inp + (size_t)slot * SLOT_STRIDE + (size_t)b * DD);

    f32x4 acc0 = {0.f, 0.f, 0.f, 0.f};      // even chunks
    f32x4 acc1 = {0.f, 0.f, 0.f, 0.f};      // odd chunks (independent chain)
    float n2a = 0.f, n2b = 0.f;             // f32 partials of ||x_slot||^2

    // chunk t covers elements [32t, 32t+32): lane takes 32t+4kg+[0..4) and
    // 32t+16+4kg+[0..4)  ->  p4[8t+kg] and p4[8t+4+kg]
#pragma unroll
    for (int tt = 0; tt < 8; ++tt) {
#pragma unroll
        for (int h = 0; h < 2; ++h) {
            const int t = 2 * tt + h;
            const float4 lo = p4[8 * t + kg];
            const float4 hi = p4[8 * t + 4 + kg];
            n2a = fmaf(lo.x, lo.x, n2a);
            n2a = fmaf(lo.y, lo.y, n2a);
            n2a = fmaf(lo.z, lo.z, n2a);
            n2a = fmaf(lo.w, lo.w, n2a);
            n2b = fmaf(hi.x, hi.x, n2b);
            n2b = fmaf(hi.y, hi.y, n2b);
            n2b = fmaf(hi.z, hi.z, n2b);
            n2b = fmaf(hi.w, hi.w, n2b);
            bf16x8 f;
            f[0] = f2bf(lo.x); f[1] = f2bf(lo.y); f[2] = f2bf(lo.z); f[3] = f2bf(lo.w);
            f[4] = f2bf(hi.x); f[5] = f2bf(hi.y); f[6] = f2bf(hi.z); f[7] = f2bf(hi.w);
            if (h == 0)
                acc0 = __builtin_amdgcn_mfma_f32_16x16x32_bf16(f, f, acc0, 0, 0, 0);
            else
                acc1 = __builtin_amdgcn_mfma_f32_16x16x32_bf16(f, f, acc1, 0, 0, 0);
        }
    }
    const f32x4 acc = acc0 + acc1;

    // exact f32 norms: lanes {slot, slot+16, slot+32, slot+48} cover slot fully
    float n2 = n2a + n2b;
    n2 += __shfl_xor(n2, 16);
    n2 += __shfl_xor(n2, 32);
    const float invc = 1.0f / fmaxf(sqrtf(n2), NORM_EPS);  // 1/||x_slot||

    // C/D layout (m89): lane holds G[4kg + r][slot] in acc[r].
    // Even rows 4kg, 4kg+2 are anchors (crops 2kg, 2kg+1, view 0).
    const float inv0 = __shfl(invc, 4 * kg);       // 1/||x_{4kg}||
    const float inv2 = __shfl(invc, 4 * kg + 2);   // 1/||x_{4kg+2}||

    const float s0 = acc[0] * inv0 * invc * INV_T;  // sim[anchor 2kg  ][slot]
    const float s2 = acc[2] * inv2 * invc * INV_T;  // sim[anchor 2kg+1][slot]

    // positives: sim[2a][2a+1] lives on the lane whose slot == anchor_slot+1
    const int gbase = kg << 4;
    const float pos0 = __shfl(s0, gbase + 4 * kg + 1);
    const float pos1 = __shfl(s2, gbase + 4 * kg + 3);

    // exclude same-crop targets (slots 2a, 2a+1), sum exp over remaining 14
    float e0 = ((slot >> 1) == 2 * kg)     ? 0.f : __expf(s0 - pos0);
    float e1 = ((slot >> 1) == 2 * kg + 1) ? 0.f : __expf(s2 - pos1);
#pragma unroll
    for (int m = 1; m < 16; m <<= 1) {
        e0 += __shfl_xor(e0, m);
        e1 += __shfl_xor(e1, m);
    }
    // loss[a][b] = log(1 + S_a); sum 2 anchors of this group, then 4 groups
    float l = __logf(1.0f + e0) + __logf(1.0f + e1);
    l += __shfl_xor(l, 16);
    l += __shfl_xor(l, 32);   // sum over all 8 anchors for this b

    __shared__ float s_wsum[4];
    if (lane == 0) s_wsum[wv] = l;
    __syncthreads();
    if (threadIdx.x == 0) {
        atomicAdd(out, (s_wsum[0] + s_wsum[1] + s_wsum[2] + s_wsum[3]) *
                           (1.0f / (float)(CC * BB)));
    }
}

extern "C" void kernel_launch(void* const* d_in, const int* in_sizes, int n_in,
                              void* d_out, int out_size, void* d_ws, size_t ws_size,
                              hipStream_t stream) {
    const float* inp = (const float*)d_in[0];
    float* out = (float*)d_out;
    hipMemsetAsync(out, 0, sizeof(float), stream);
    ntxent_mfma<<<dim3(BB / 4), dim3(256), 0, stream>>>(inp, out);
}

// Round 4
// 29.681 us; speedup vs baseline: 1.4836x; 1.4305x over previous
//
#include <hip/hip_runtime.h>
#include <hip/hip_bf16.h>
#include <math.h>

#define CC 8
#define BB 4096
#define DD 512
#define SLOT_STRIDE (BB * DD)   // elements between (c,v) slots

constexpr float INV_T    = 10.0f;    // 1 / 0.1
constexpr float NORM_EPS = 1e-12f;

typedef __attribute__((ext_vector_type(8))) short bf16x8;  // 8 bf16 (4 VGPRs)
typedef __attribute__((ext_vector_type(4))) float f32x4;   // 4 fp32 acc

__device__ __forceinline__ short f2bf(float x) {
    union { __hip_bfloat16 h; short s; } u;
    u.h = __float2bfloat16(x);
    return u.s;
}

// One wave per batch column b. The 16 vectors (slots) of column b form
// X (16 x 512). Gram G = X X^T via 16x16x32 bf16 MFMA with A-frag == B-frag
// (identical lane mapping: row/col = lane&15). Because BOTH operands come
// from the same registers, any shared element->k permutation cancels exactly.
// Norms kept exact in f32. Per-block partial written to d_ws; a second
// 1-block kernel reduces (avoids 1024 same-address atomicAdds draining
// serialized at one TCC bank at kernel end).
__global__ __launch_bounds__(256, 4)   // cap VGPR at 128 -> 4 waves/SIMD
void ntxent_mfma(const float* __restrict__ inp, float* __restrict__ partial) {
    const int lane = threadIdx.x & 63;
    const int wv   = threadIdx.x >> 6;      // wave in block: 0..3
    const int b    = blockIdx.x * 4 + wv;   // batch column
    const int slot = lane & 15;             // vector index = MFMA row & col
    const int kg   = lane >> 4;             // quarter-wave 0..3

    const float4* p4 = reinterpret_cast<const float4*>(
        inp + (size_t)slot * SLOT_STRIDE + (size_t)b * DD);

    f32x4 acc0 = {0.f, 0.f, 0.f, 0.f};      // even chunks
    f32x4 acc1 = {0.f, 0.f, 0.f, 0.f};      // odd chunks (independent chain)
    float n2a = 0.f, n2b = 0.f;             // f32 partials of ||x_slot||^2

    // chunk t covers elements [32t, 32t+32): lane takes 32t+4kg+[0..4) and
    // 32t+16+4kg+[0..4)  ->  p4[8t+kg] and p4[8t+4+kg]
#pragma unroll
    for (int tt = 0; tt < 8; ++tt) {
#pragma unroll
        for (int h = 0; h < 2; ++h) {
            const int t = 2 * tt + h;
            const float4 lo = p4[8 * t + kg];
            const float4 hi = p4[8 * t + 4 + kg];
            n2a = fmaf(lo.x, lo.x, n2a);
            n2a = fmaf(lo.y, lo.y, n2a);
            n2a = fmaf(lo.z, lo.z, n2a);
            n2a = fmaf(lo.w, lo.w, n2a);
            n2b = fmaf(hi.x, hi.x, n2b);
            n2b = fmaf(hi.y, hi.y, n2b);
            n2b = fmaf(hi.z, hi.z, n2b);
            n2b = fmaf(hi.w, hi.w, n2b);
            bf16x8 f;
            f[0] = f2bf(lo.x); f[1] = f2bf(lo.y); f[2] = f2bf(lo.z); f[3] = f2bf(lo.w);
            f[4] = f2bf(hi.x); f[5] = f2bf(hi.y); f[6] = f2bf(hi.z); f[7] = f2bf(hi.w);
            if (h == 0)
                acc0 = __builtin_amdgcn_mfma_f32_16x16x32_bf16(f, f, acc0, 0, 0, 0);
            else
                acc1 = __builtin_amdgcn_mfma_f32_16x16x32_bf16(f, f, acc1, 0, 0, 0);
        }
    }
    const f32x4 acc = acc0 + acc1;

    // exact f32 norms: lanes {slot, slot+16, slot+32, slot+48} cover slot fully
    float n2 = n2a + n2b;
    n2 += __shfl_xor(n2, 16);
    n2 += __shfl_xor(n2, 32);
    const float invc = 1.0f / fmaxf(sqrtf(n2), NORM_EPS);  // 1/||x_slot||

    // C/D layout (m89): lane holds G[4kg + r][slot] in acc[r].
    // Even rows 4kg, 4kg+2 are anchors (crops 2kg, 2kg+1, view 0).
    const float inv0 = __shfl(invc, 4 * kg);       // 1/||x_{4kg}||
    const float inv2 = __shfl(invc, 4 * kg + 2);   // 1/||x_{4kg+2}||

    const float s0 = acc[0] * inv0 * invc * INV_T;  // sim[anchor 2kg  ][slot]
    const float s2 = acc[2] * inv2 * invc * INV_T;  // sim[anchor 2kg+1][slot]

    // positives: sim[2a][2a+1] lives on the lane whose slot == anchor_slot+1
    const int gbase = kg << 4;
    const float pos0 = __shfl(s0, gbase + 4 * kg + 1);
    const float pos1 = __shfl(s2, gbase + 4 * kg + 3);

    // exclude same-crop targets (slots 2a, 2a+1), sum exp over remaining 14
    float e0 = ((slot >> 1) == 2 * kg)     ? 0.f : __expf(s0 - pos0);
    float e1 = ((slot >> 1) == 2 * kg + 1) ? 0.f : __expf(s2 - pos1);
#pragma unroll
    for (int m = 1; m < 16; m <<= 1) {
        e0 += __shfl_xor(e0, m);
        e1 += __shfl_xor(e1, m);
    }
    // loss[a][b] = log(1 + S_a); sum 2 anchors of this group, then 4 groups
    float l = __logf(1.0f + e0) + __logf(1.0f + e1);
    l += __shfl_xor(l, 16);
    l += __shfl_xor(l, 32);   // sum over all 8 anchors for this b

    __shared__ float s_wsum[4];
    if (lane == 0) s_wsum[wv] = l;
    __syncthreads();
    if (threadIdx.x == 0)
        partial[blockIdx.x] = s_wsum[0] + s_wsum[1] + s_wsum[2] + s_wsum[3];
}

// Sum the 1024 per-block partials -> scalar loss. One block.
__global__ __launch_bounds__(256)
void ntxent_reduce(const float* __restrict__ partial, float* __restrict__ out) {
    const int tid = threadIdx.x;
    const float4 v = reinterpret_cast<const float4*>(partial)[tid];  // 256*4 = 1024
    float s = v.x + v.y + v.z + v.w;
#pragma unroll
    for (int m = 1; m < 64; m <<= 1) s += __shfl_xor(s, m);
    __shared__ float ws[4];
    if ((tid & 63) == 0) ws[tid >> 6] = s;
    __syncthreads();
    if (tid == 0)
        out[0] = (ws[0] + ws[1] + ws[2] + ws[3]) * (1.0f / (float)(CC * BB));
}

extern "C" void kernel_launch(void* const* d_in, const int* in_sizes, int n_in,
                              void* d_out, int out_size, void* d_ws, size_t ws_size,
                              hipStream_t stream) {
    const float* inp = (const float*)d_in[0];
    float* out      = (float*)d_out;
    float* partial  = (float*)d_ws;   // 1024 floats, fully rewritten every call
    ntxent_mfma<<<dim3(BB / 4), dim3(256), 0, stream>>>(inp, partial);
    ntxent_reduce<<<dim3(1), dim3(256), 0, stream>>>(partial, out);
}